// Round 2
// baseline (1954.800 us; speedup 1.0000x reference)
//
#include <hip/hip_runtime.h>
#include <math.h>

#define NBATCH 2048
#define NT 64
#define KK 40
#define NL 7
#define HSTR (KK*2)      // 80 floats: interleaved (re,im), row stride for H/W/G
#define SSTR (KK*2+4)    // 84 floats: padded row stride for S (bank-conflict fix)
#define SIGMA 0.02f
#define INVLN2 1.4426950408889634f

__global__ __launch_bounds__(256) void gpnet_kernel(
    const float* __restrict__ gHr, const float* __restrict__ gHi,
    const float* __restrict__ gEta, const float* __restrict__ gU,
    const float* __restrict__ gB, float* __restrict__ gOut, int outFloats)
{
    __shared__ __align__(16) float sH[NT*HSTR];
    __shared__ __align__(16) float sW[NT*HSTR];
    __shared__ __align__(16) float sG[NT*HSTR];
    __shared__ __align__(16) float sS[KK*SSTR];
    __shared__ __align__(16) float sU[NT*NT];
    __shared__ float sRed[4];
    __shared__ float sPw;

    const int tid = threadIdx.x;
    const int bb  = blockIdx.x;
    const float* hr = gHr + (size_t)bb * NT * KK;
    const float* hi = gHi + (size_t)bb * NT * KK;

    // Load H (interleaved), zero W
    for (int i = tid; i < NT*KK; i += 256) {
        int n = i / KK, k = i % KK;
        sH[n*HSTR + 2*k]     = hr[i];
        sH[n*HSTR + 2*k + 1] = hi[i];
        sW[n*HSTR + 2*k]     = 0.f;
        sW[n*HSTR + 2*k + 1] = 0.f;
    }
    __syncthreads();

    for (int t = 0; t < NL; ++t) {
        // stage U[t] (coalesced)
        for (int i = tid; i < NT*NT; i += 256)
            sU[i] = gU[t*NT*NT + i];

        // power = ||W||_F^2 of current W
        float ps = 0.f;
        for (int i = tid; i < NT*KK; i += 256) {
            int n = i / KK, k = i % KK;
            float wr = sW[n*HSTR + 2*k], wi = sW[n*HSTR + 2*k + 1];
            ps += wr*wr + wi*wi;
        }
        #pragma unroll
        for (int off = 32; off; off >>= 1) ps += __shfl_down(ps, off, 64);
        if ((tid & 63) == 0) sRed[tid >> 6] = ps;
        __syncthreads();                                      // (1)
        if (tid == 0) sPw = sRed[0] + sRed[1] + sRed[2] + sRed[3];

        // ---- A: S[k][l] = sum_n conj(H[n,k]) * W[n,l]  (tiles 4k x 2l, 200 tiles)
        if (tid < 200) {
            const int k0 = (tid / 20) * 4;
            const int l0 = (tid % 20) * 2;
            float ar[4][2] = {{0.f,0.f},{0.f,0.f},{0.f,0.f},{0.f,0.f}};
            float ai[4][2] = {{0.f,0.f},{0.f,0.f},{0.f,0.f},{0.f,0.f}};
            #pragma unroll 4
            for (int n = 0; n < NT; ++n) {
                const float* hp = &sH[n*HSTR + 2*k0];
                float4 h01 = *(const float4*)(hp);
                float4 h23 = *(const float4*)(hp + 4);
                float4 w01 = *(const float4*)&sW[n*HSTR + 2*l0];
                float hre[4] = {h01.x, h01.z, h23.x, h23.z};
                float him[4] = {h01.y, h01.w, h23.y, h23.w};
                float wre[2] = {w01.x, w01.z};
                float wim[2] = {w01.y, w01.w};
                #pragma unroll
                for (int i = 0; i < 4; ++i)
                    #pragma unroll
                    for (int j = 0; j < 2; ++j) {
                        ar[i][j] += hre[i]*wre[j] + him[i]*wim[j];
                        ai[i][j] += hre[i]*wim[j] - him[i]*wre[j];
                    }
            }
            #pragma unroll
            for (int i = 0; i < 4; ++i)
                #pragma unroll
                for (int j = 0; j < 2; ++j) {
                    sS[(k0+i)*SSTR + 2*(l0+j)]     = ar[i][j];
                    sS[(k0+i)*SSTR + 2*(l0+j) + 1] = ai[i][j];
                }
        }
        __syncthreads();                                      // (2)

        // ---- coefficients + scale S rows in place (thread k owns row k)
        if (tid < KK) {
            const int k = tid;
            float rs = 0.f, d = 0.f;
            for (int l = 0; l < KK; ++l) {
                float pr = sS[k*SSTR + 2*l], pi = sS[k*SSTR + 2*l + 1];
                float pw = pr*pr + pi*pi;
                rs += pw;
                if (l == k) d = pw;
            }
            float T  = rs + SIGMA;              // d + I + sigma
            float Is = rs - d + SIGMA;          // I + sigma
            float cA = 2.f * INVLN2 / T;
            float cC = -2.f * INVLN2 * d / (Is * T);
            for (int l = 0; l < KK; ++l) {
                float c = (l == k) ? cA : cC;
                sS[k*SSTR + 2*l]     *= c;
                sS[k*SSTR + 2*l + 1] *= c;
            }
        }
        __syncthreads();                                      // (3)

        // ---- B: G = H @ S - cp*W   (tiles 4n x 2l over 64x40, 320 tiles)
        const float cp = 0.04f * (sPw - 1.0f);
        for (int tt = tid; tt < 320; tt += 256) {
            const int n0 = (tt / 20) * 4;
            const int l0 = (tt % 20) * 2;
            float gr[4][2] = {{0.f,0.f},{0.f,0.f},{0.f,0.f},{0.f,0.f}};
            float gi[4][2] = {{0.f,0.f},{0.f,0.f},{0.f,0.f},{0.f,0.f}};
            #pragma unroll 2
            for (int k = 0; k < KK; k += 2) {
                float4 s0 = *(const float4*)&sS[k*SSTR + 2*l0];
                float4 s1 = *(const float4*)&sS[(k+1)*SSTR + 2*l0];
                #pragma unroll
                for (int i = 0; i < 4; ++i) {
                    float4 h = *(const float4*)&sH[(n0+i)*HSTR + 2*k];
                    gr[i][0] += h.x*s0.x - h.y*s0.y;  gi[i][0] += h.x*s0.y + h.y*s0.x;
                    gr[i][1] += h.x*s0.z - h.y*s0.w;  gi[i][1] += h.x*s0.w + h.y*s0.z;
                    gr[i][0] += h.z*s1.x - h.w*s1.y;  gi[i][0] += h.z*s1.y + h.w*s1.x;
                    gr[i][1] += h.z*s1.z - h.w*s1.w;  gi[i][1] += h.z*s1.w + h.w*s1.z;
                }
            }
            #pragma unroll
            for (int i = 0; i < 4; ++i)
                #pragma unroll
                for (int j = 0; j < 2; ++j) {
                    int idx = (n0+i)*HSTR + 2*(l0+j);
                    sG[idx]     = gr[i][j] - cp * sW[idx];
                    sG[idx + 1] = gi[i][j] - cp * sW[idx + 1];
                }
        }
        __syncthreads();                                      // (4)

        // ---- C: Ug = U @ G; W -= eta*(1+i)*Ug, += b (real)  (tiles 4n x 2k)
        const float etat = gEta[t];
        for (int tt = tid; tt < 320; tt += 256) {
            const int n0 = (tt / 20) * 4;
            const int k0 = (tt % 20) * 2;
            float ur[4][2] = {{0.f,0.f},{0.f,0.f},{0.f,0.f},{0.f,0.f}};
            float ui[4][2] = {{0.f,0.f},{0.f,0.f},{0.f,0.f},{0.f,0.f}};
            #pragma unroll 2
            for (int m = 0; m < NT; m += 4) {
                float4 g0 = *(const float4*)&sG[m*HSTR + 2*k0];
                float4 g1 = *(const float4*)&sG[(m+1)*HSTR + 2*k0];
                float4 g2 = *(const float4*)&sG[(m+2)*HSTR + 2*k0];
                float4 g3 = *(const float4*)&sG[(m+3)*HSTR + 2*k0];
                #pragma unroll
                for (int i = 0; i < 4; ++i) {
                    float4 u = *(const float4*)&sU[(n0+i)*NT + m];
                    ur[i][0] += u.x*g0.x + u.y*g1.x + u.z*g2.x + u.w*g3.x;
                    ui[i][0] += u.x*g0.y + u.y*g1.y + u.z*g2.y + u.w*g3.y;
                    ur[i][1] += u.x*g0.z + u.y*g1.z + u.z*g2.z + u.w*g3.z;
                    ui[i][1] += u.x*g0.w + u.y*g1.w + u.z*g2.w + u.w*g3.w;
                }
            }
            #pragma unroll
            for (int i = 0; i < 4; ++i)
                #pragma unroll
                for (int j = 0; j < 2; ++j) {
                    int n = n0 + i, k = k0 + j;
                    int idx = n*HSTR + 2*k;
                    float br = gB[t*NT*KK + n*KK + k];
                    float stepr = ur[i][j] - ui[i][j];
                    float stepi = ui[i][j] + ur[i][j];
                    sW[idx]     = sW[idx]     - etat*stepr + br;
                    sW[idx + 1] = sW[idx + 1] - etat*stepi;
                }
        }
        __syncthreads();                                      // (5)
    }

    // ---- final normalization
    float ps = 0.f;
    for (int i = tid; i < NT*KK; i += 256) {
        int n = i / KK, k = i % KK;
        float wr = sW[n*HSTR + 2*k], wi = sW[n*HSTR + 2*k + 1];
        ps += wr*wr + wi*wi;
    }
    #pragma unroll
    for (int off = 32; off; off >>= 1) ps += __shfl_down(ps, off, 64);
    if ((tid & 63) == 0) sRed[tid >> 6] = ps;
    __syncthreads();
    float norm  = sqrtf(sRed[0] + sRed[1] + sRed[2] + sRed[3]);
    float scale = 1.0f / (norm + 1e-6f);

    // Output: harness evidence says d_out = real part only (B*Nt*K floats).
    // Branch on out_size (wave-uniform, deterministic) to be robust either way.
    if (outFloats >= 2 * NBATCH * NT * KK) {
        // interleaved complex64 view
        float2* ob = (float2*)(gOut + (size_t)bb * NT * KK * 2);
        for (int i = tid; i < NT*KK; i += 256) {
            int n = i / KK, k = i % KK;
            float2 v;
            v.x = sW[n*HSTR + 2*k]     * scale;
            v.y = sW[n*HSTR + 2*k + 1] * scale;
            ob[i] = v;
        }
    } else {
        // real part only
        float* ob = gOut + (size_t)bb * NT * KK;
        for (int i = tid; i < NT*KK; i += 256) {
            int n = i / KK, k = i % KK;
            ob[i] = sW[n*HSTR + 2*k] * scale;
        }
    }
}

extern "C" void kernel_launch(void* const* d_in, const int* in_sizes, int n_in,
                              void* d_out, int out_size, void* d_ws, size_t ws_size,
                              hipStream_t stream) {
    (void)in_sizes; (void)n_in; (void)d_ws; (void)ws_size;
    const float* Hr  = (const float*)d_in[0];
    const float* Hi  = (const float*)d_in[1];
    const float* eta = (const float*)d_in[2];
    const float* U   = (const float*)d_in[3];
    const float* b   = (const float*)d_in[4];
    float* out = (float*)d_out;
    gpnet_kernel<<<NBATCH, 256, 0, stream>>>(Hr, Hi, eta, U, b, out, out_size);
}

// Round 3
// 956.228 us; speedup vs baseline: 2.0443x; 2.0443x over previous
//
#include <hip/hip_runtime.h>
#include <math.h>

#define NBATCH 2048
#define NT 64
#define KK 40
#define NL 7
#define HSTR 84      // floats; 336B row stride -> mod-128 walks all 8 slots
#define USTR 68      // floats; 272B row stride -> mod-128 walks all 8 slots
#define SSTR 84
#define SIGMA 0.02f
#define INVLN2 1.4426950408889634f

__global__ __launch_bounds__(256) void gpnet_kernel(
    const float* __restrict__ gHr, const float* __restrict__ gHi,
    const float* __restrict__ gEta, const float* __restrict__ gU,
    const float* __restrict__ gB, float* __restrict__ gOut)
{
    // sHU: holds H (64 x HSTR interleaved) in phases A/B, U[t] (64 x USTR) in phase C
    __shared__ __align__(16) float sHU[NT*HSTR];
    __shared__ __align__(16) float sW[NT*HSTR];
    __shared__ __align__(16) float sG[NT*HSTR];
    __shared__ __align__(16) float sS[KK*SSTR];
    __shared__ float sRed[4];

    const int tid = threadIdx.x;
    const int wid = tid >> 6;
    const int bb  = blockIdx.x;
    const float* hr = gHr + (size_t)bb * NT * KK;
    const float* hi = gHi + (size_t)bb * NT * KK;

    const int n0 = (tid >> 3) << 1;     // 0..62 even   (phase B/C row base)
    const int c0 = (tid & 7) * 5;       // 0..35        (phase B/C col base)

    // ---- init: load H, W = b[0] (layer 0 collapses: grad(W=0)=0), power = ||b0||^2
    float ps = 0.f;
    for (int i = tid; i < NT*KK; i += 256) {
        int n = i / KK, k = i % KK;
        float2 h; h.x = hr[i]; h.y = hi[i];
        *(float2*)&sHU[n*HSTR + 2*k] = h;
        float br = gB[i];
        float2 w; w.x = br; w.y = 0.f;
        *(float2*)&sW[n*HSTR + 2*k] = w;
        ps += br * br;
    }
    #pragma unroll
    for (int off = 32; off; off >>= 1) ps += __shfl_down(ps, off, 64);
    if ((tid & 63) == 0) sRed[wid] = ps;
    __syncthreads();

    for (int t = 1; t < NL; ++t) {
        const float pw   = sRed[0] + sRed[1] + sRed[2] + sRed[3];
        const float cp   = 0.04f * (pw - 1.0f);
        const float etat = gEta[t];

        // early global loads (hidden under phases A..B): U[t] and b[t]
        float4 ureg[4];
        const float4* up = (const float4*)(gU + (size_t)t * NT * NT);
        #pragma unroll
        for (int j = 0; j < 4; ++j) ureg[j] = up[tid + j*256];
        float breg[2][5];
        #pragma unroll
        for (int i = 0; i < 2; ++i)
            #pragma unroll
            for (int j = 0; j < 5; ++j)
                breg[i][j] = gB[(size_t)t*NT*KK + (n0+i)*KK + c0 + j];

        // ---- A: S[k][l] = sum_n conj(H[n,k]) * W[n,l]   (4k x 2l tiles, 200 thr)
        if (tid < 200) {
            const int k0 = (tid / 20) * 4;
            const int l0 = (tid % 20) * 2;
            float ar[4][2] = {{0.f,0.f},{0.f,0.f},{0.f,0.f},{0.f,0.f}};
            float ai[4][2] = {{0.f,0.f},{0.f,0.f},{0.f,0.f},{0.f,0.f}};
            #pragma unroll 4
            for (int n = 0; n < NT; ++n) {
                const float* hp = &sHU[n*HSTR + 2*k0];
                float4 h01 = *(const float4*)(hp);
                float4 h23 = *(const float4*)(hp + 4);
                float4 w01 = *(const float4*)&sW[n*HSTR + 2*l0];
                float hre[4] = {h01.x, h01.z, h23.x, h23.z};
                float him[4] = {h01.y, h01.w, h23.y, h23.w};
                float wre[2] = {w01.x, w01.z};
                float wim[2] = {w01.y, w01.w};
                #pragma unroll
                for (int i = 0; i < 4; ++i)
                    #pragma unroll
                    for (int j = 0; j < 2; ++j) {
                        ar[i][j] += hre[i]*wre[j] + him[i]*wim[j];
                        ai[i][j] += hre[i]*wim[j] - him[i]*wre[j];
                    }
            }
            #pragma unroll
            for (int i = 0; i < 4; ++i)
                #pragma unroll
                for (int j = 0; j < 2; ++j) {
                    sS[(k0+i)*SSTR + 2*(l0+j)]     = ar[i][j];
                    sS[(k0+i)*SSTR + 2*(l0+j) + 1] = ai[i][j];
                }
        }
        __syncthreads();                                   // (2)

        // ---- coefficients: 4 lanes per row k, scale S in place
        if (tid < 160) {
            const int k = tid >> 2, q = tid & 3;
            float rs = 0.f, d = 0.f;
            for (int l = q*10; l < q*10 + 10; ++l) {
                float pr = sS[k*SSTR + 2*l], pi = sS[k*SSTR + 2*l + 1];
                float pwl = pr*pr + pi*pi;
                rs += pwl;
                if (l == k) d = pwl;
            }
            rs += __shfl_xor(rs, 1, 64); rs += __shfl_xor(rs, 2, 64);
            d  += __shfl_xor(d, 1, 64);  d  += __shfl_xor(d, 2, 64);
            float T  = rs + SIGMA;
            float Is = rs - d + SIGMA;
            float cA = 2.f * INVLN2 / T;
            float cC = -2.f * INVLN2 * d / (Is * T);
            for (int l = q*10; l < q*10 + 10; ++l) {
                float c = (l == k) ? cA : cC;
                sS[k*SSTR + 2*l]     *= c;
                sS[k*SSTR + 2*l + 1] *= c;
            }
        }
        __syncthreads();                                   // (3)

        // ---- B: G = H @ S' - cp*W   (2n x 5l tiles, exactly 256 threads)
        {
            float gr[2][5] = {}, gi[2][5] = {};
            #pragma unroll 2
            for (int k = 0; k < KK; k += 2) {
                float4 h0 = *(const float4*)&sHU[(n0  )*HSTR + 2*k];
                float4 h1 = *(const float4*)&sHU[(n0+1)*HSTR + 2*k];
                #pragma unroll
                for (int j = 0; j < 5; ++j) {
                    float2 s0 = *(const float2*)&sS[(k  )*SSTR + 2*(c0+j)];
                    float2 s1 = *(const float2*)&sS[(k+1)*SSTR + 2*(c0+j)];
                    gr[0][j] += h0.x*s0.x - h0.y*s0.y;  gi[0][j] += h0.x*s0.y + h0.y*s0.x;
                    gr[0][j] += h0.z*s1.x - h0.w*s1.y;  gi[0][j] += h0.z*s1.y + h0.w*s1.x;
                    gr[1][j] += h1.x*s0.x - h1.y*s0.y;  gi[1][j] += h1.x*s0.y + h1.y*s0.x;
                    gr[1][j] += h1.z*s1.x - h1.w*s1.y;  gi[1][j] += h1.z*s1.y + h1.w*s1.x;
                }
            }
            #pragma unroll
            for (int i = 0; i < 2; ++i)
                #pragma unroll
                for (int j = 0; j < 5; ++j) {
                    int idx = (n0+i)*HSTR + 2*(c0+j);
                    sG[idx]     = gr[i][j] - cp * sW[idx];
                    sG[idx + 1] = gi[i][j] - cp * sW[idx + 1];
                }
        }
        __syncthreads();                                   // (4) H dead, G ready

        // U regs -> sHU as [64][USTR]
        #pragma unroll
        for (int j = 0; j < 4; ++j) {
            int f = 4 * (tid + j*256);          // flat idx in 64x64
            int r = f >> 6, c = f & 63;
            *(float4*)&sHU[r*USTR + c] = ureg[j];
        }
        // issue H reload (consumed after barrier 5)
        float2 hrr[5], hri[5];
        if (t < NL-1) {
            const float2* h2r = (const float2*)hr;
            const float2* h2i = (const float2*)hi;
            #pragma unroll
            for (int j = 0; j < 5; ++j) {
                hrr[j] = h2r[tid + j*256];
                hri[j] = h2i[tid + j*256];
            }
        }
        __syncthreads();                                   // (4b) U visible

        // ---- C: Ug = U @ G; W update; fold ||W||^2 reduction
        {
            float ur[2][5] = {}, ui[2][5] = {};
            #pragma unroll 2
            for (int m = 0; m < NT; m += 4) {
                float4 u0 = *(const float4*)&sHU[(n0  )*USTR + m];
                float4 u1 = *(const float4*)&sHU[(n0+1)*USTR + m];
                #pragma unroll
                for (int j = 0; j < 5; ++j) {
                    float2 g0 = *(const float2*)&sG[(m+0)*HSTR + 2*(c0+j)];
                    float2 g1 = *(const float2*)&sG[(m+1)*HSTR + 2*(c0+j)];
                    float2 g2 = *(const float2*)&sG[(m+2)*HSTR + 2*(c0+j)];
                    float2 g3 = *(const float2*)&sG[(m+3)*HSTR + 2*(c0+j)];
                    ur[0][j] += u0.x*g0.x + u0.y*g1.x + u0.z*g2.x + u0.w*g3.x;
                    ui[0][j] += u0.x*g0.y + u0.y*g1.y + u0.z*g2.y + u0.w*g3.y;
                    ur[1][j] += u1.x*g0.x + u1.y*g1.x + u1.z*g2.x + u1.w*g3.x;
                    ui[1][j] += u1.x*g0.y + u1.y*g1.y + u1.z*g2.y + u1.w*g3.y;
                }
            }
            float ps2 = 0.f;
            #pragma unroll
            for (int i = 0; i < 2; ++i)
                #pragma unroll
                for (int j = 0; j < 5; ++j) {
                    int idx = (n0+i)*HSTR + 2*(c0+j);
                    float stepr = ur[i][j] - ui[i][j];
                    float stepi = ui[i][j] + ur[i][j];
                    float wr = sW[idx]     - etat*stepr + breg[i][j];
                    float wi = sW[idx + 1] - etat*stepi;
                    sW[idx]     = wr;
                    sW[idx + 1] = wi;
                    ps2 += wr*wr + wi*wi;
                }
            #pragma unroll
            for (int off = 32; off; off >>= 1) ps2 += __shfl_down(ps2, off, 64);
            if ((tid & 63) == 0) sRed[wid] = ps2;
        }
        __syncthreads();                                   // (5) W, sRed valid; U dead

        if (t < NL-1) {
            // write reloaded H back into sHU (interleaved, stride HSTR)
            #pragma unroll
            for (int j = 0; j < 5; ++j) {
                int e0 = 2 * (tid + j*256);
                int n_ = e0 / KK, k_ = e0 % KK;
                float2 v0; v0.x = hrr[j].x; v0.y = hri[j].x;
                *(float2*)&sHU[n_*HSTR + 2*k_] = v0;
                int e1 = e0 + 1;
                n_ = e1 / KK; k_ = e1 % KK;
                float2 v1; v1.x = hrr[j].y; v1.y = hri[j].y;
                *(float2*)&sHU[n_*HSTR + 2*k_] = v1;
            }
            __syncthreads();                               // (6) H restored
        }
    }

    // ---- final normalization (power already reduced by last phase C)
    const float pw = sRed[0] + sRed[1] + sRed[2] + sRed[3];
    const float scale = 1.0f / (sqrtf(pw) + 1e-6f);
    float* ob = gOut + (size_t)bb * NT * KK;
    for (int i = tid; i < NT*KK; i += 256) {
        int n = i / KK, k = i % KK;
        ob[i] = sW[n*HSTR + 2*k] * scale;
    }
}

extern "C" void kernel_launch(void* const* d_in, const int* in_sizes, int n_in,
                              void* d_out, int out_size, void* d_ws, size_t ws_size,
                              hipStream_t stream) {
    (void)in_sizes; (void)n_in; (void)d_ws; (void)ws_size; (void)out_size;
    const float* Hr  = (const float*)d_in[0];
    const float* Hi  = (const float*)d_in[1];
    const float* eta = (const float*)d_in[2];
    const float* U   = (const float*)d_in[3];
    const float* b   = (const float*)d_in[4];
    float* out = (float*)d_out;
    gpnet_kernel<<<NBATCH, 256, 0, stream>>>(Hr, Hi, eta, U, b, out);
}

// Round 5
// 365.506 us; speedup vs baseline: 5.3482x; 2.6162x over previous
//
#include <hip/hip_runtime.h>
#include <math.h>

typedef _Float16 h16;
typedef __attribute__((ext_vector_type(2))) _Float16 h16x2;
typedef __attribute__((ext_vector_type(4))) _Float16 h16x4;
typedef __attribute__((ext_vector_type(8))) _Float16 h16x8;

#define NBATCH 2048
#define NT 64
#define KK 40
#define NL 7
#define SIGMA 0.02f
#define INVLN2 1.4426950408889634f

// LDS layout (units: h16x2 = 4B)
#define OFF_H   0                   // H  [64][44]  (hr,hi), k-contiguous
#define OFF_WAB (64*44)             // W  [64][40]  (wr,wi)
#define OFF_WBA (OFF_WAB + 64*40)   // W  [64][40]  (wi,-wr)
#define OFF_SAB (OFF_WBA + 64*40)   // S^T[40][44]  (sr,-si); G overlay [40][34] (gr pairs)
#define OFF_SBA (OFF_SAB + 40*44)   // S^T[40][44]  (si, sr); G overlay [40][34] (gi pairs)
#define OFF_UP  (OFF_SBA + 40*44)   // U  [64][34]  (u[m],u[m+1]) packed m-pairs
#define LDS_H2  (OFF_UP + 64*34)    // = 13632 h16x2 = 54528 B

static __device__ __forceinline__ float DOT2(h16x2 a, h16x2 b, float c) {
#if __has_builtin(__builtin_amdgcn_fdot2)
    return __builtin_amdgcn_fdot2(a, b, c, false);
#else
    return fmaf((float)a.x, (float)b.x, fmaf((float)a.y, (float)b.y, c));
#endif
}
static __device__ __forceinline__ h16x2 PK(float x, float y) {
    h16x2 r; r.x = (h16)x; r.y = (h16)y; return r;
}
// pair extractors: parse-time legal with runtime index; all call sites are in
// fully-unrolled loops so indices constant-fold and SROA keeps regs.
static __device__ __forceinline__ h16x2 GET8(h16x8 v, int i) {
    union { h16x8 w; h16x2 p[4]; } u; u.w = v; return u.p[i];
}
static __device__ __forceinline__ h16x2 GET4(h16x4 v, int i) {
    union { h16x4 w; h16x2 p[2]; } u; u.w = v; return u.p[i];
}

__global__ __launch_bounds__(256, 3) void gpnet_kernel(
    const float* __restrict__ gHr, const float* __restrict__ gHi,
    const float* __restrict__ gEta, const float* __restrict__ gU,
    const float* __restrict__ gB, float* __restrict__ gOut, int outFloats)
{
    __shared__ __align__(16) h16x2 sh[LDS_H2];
    __shared__ float sRed[4];

    const int tid = threadIdx.x;
    const int wid = tid >> 6;
    const int bb  = blockIdx.x;
    const float* hr = gHr + (size_t)bb * NT * KK;
    const float* hi = gHi + (size_t)bb * NT * KK;

    // B/C/W-ownership tile: rows (n0, n0+1), cols c0..c0+4
    const int n0  = (tid >> 3) << 1;     // 0,2,...,62
    const int c0  = (tid & 7) * 5;       // 0,5,...,35
    const int nn0 = tid >> 3;            // m-pair index for G

    // A-phase tile (first 200 threads): S rows k0..k0+3, cols l0,l0+1
    const int k0 = (tid / 20) * 4;
    const int l0 = (tid % 20) * 2;

    // ---- init: H -> LDS (fp16 packed); W = b[0] in regs; packed W -> LDS; power
    float Wr[2][5], Wi[2][5];
    {
        for (int i = tid; i < NT*KK; i += 256) {
            int n = i / KK, k = i % KK;
            sh[OFF_H + n*44 + k] = PK(hr[i], hi[i]);
        }
        float ps = 0.f;
        #pragma unroll
        for (int i = 0; i < 2; ++i)
            #pragma unroll
            for (int j = 0; j < 5; ++j) {
                float br = gB[(n0+i)*KK + c0 + j];
                Wr[i][j] = br; Wi[i][j] = 0.f;
                sh[OFF_WAB + (n0+i)*40 + c0+j] = PK(br, 0.f);
                sh[OFF_WBA + (n0+i)*40 + c0+j] = PK(0.f, -br);
                ps += br * br;
            }
        #pragma unroll
        for (int off = 32; off; off >>= 1) ps += __shfl_down(ps, off, 64);
        if ((tid & 63) == 0) sRed[wid] = ps;
    }
    __syncthreads();

    for (int t = 1; t < NL; ++t) {
        const float pw   = sRed[0] + sRed[1] + sRed[2] + sRed[3];
        const float cp   = 0.04f * (pw - 1.0f);
        const float etat = gEta[t];

        // early global loads (hidden under A/coeff/B): U[t] (float2 pairs) and b[t]
        float2 ureg[8];
        {
            const float2* u2 = (const float2*)(gU + (size_t)t * NT * NT);
            #pragma unroll
            for (int j = 0; j < 8; ++j) ureg[j] = u2[tid + j*256];
        }
        float breg[2][5];
        #pragma unroll
        for (int i = 0; i < 2; ++i)
            #pragma unroll
            for (int j = 0; j < 5; ++j)
                breg[i][j] = gB[(size_t)t*NT*KK + (n0+i)*KK + c0 + j];

        // ---- A: S[k][l] = sum_n conj(H[n,k]) W[n,l]; write S^T fp16 (two packed forms)
        if (tid < 200) {
            float ar[4][2] = {}, ai[4][2] = {};
            #pragma unroll 2
            for (int n = 0; n < NT; ++n) {
                h16x8 hv  = *(const h16x8*)(sh + OFF_H   + n*44 + k0);
                h16x4 wav = *(const h16x4*)(sh + OFF_WAB + n*40 + l0);
                h16x4 wbv = *(const h16x4*)(sh + OFF_WBA + n*40 + l0);
                h16x2 wa0 = GET4(wav,0), wa1 = GET4(wav,1);
                h16x2 wb0 = GET4(wbv,0), wb1 = GET4(wbv,1);
                #pragma unroll
                for (int i = 0; i < 4; ++i) {
                    h16x2 h_ = GET8(hv,i);
                    ar[i][0] = DOT2(h_, wa0, ar[i][0]);   // hr*wr + hi*wi
                    ar[i][1] = DOT2(h_, wa1, ar[i][1]);
                    ai[i][0] = DOT2(h_, wb0, ai[i][0]);   // hr*wi - hi*wr
                    ai[i][1] = DOT2(h_, wb1, ai[i][1]);
                }
            }
            #pragma unroll
            for (int j = 0; j < 2; ++j) {
                h16x8 sa, sb;
                #pragma unroll
                for (int i = 0; i < 4; ++i) {
                    sa[2*i]   = (h16)ar[i][j];  sa[2*i+1] = (h16)(-ai[i][j]);
                    sb[2*i]   = (h16)ai[i][j];  sb[2*i+1] = (h16)ar[i][j];
                }
                *(h16x8*)(sh + OFF_SAB + (l0+j)*44 + k0) = sa;
                *(h16x8*)(sh + OFF_SBA + (l0+j)*44 + k0) = sb;
            }
        }
        __syncthreads();                                   // (1)

        // ---- coefficients: 4 lanes per user k (column k of S^T); scale in place
        if (tid < 160) {
            const int k = tid >> 2, q = tid & 3;
            h16x2 va[10], vb[10];
            #pragma unroll
            for (int ii = 0; ii < 10; ++ii)
                va[ii] = sh[OFF_SAB + (q*10+ii)*44 + k];
            float rs = 0.f, d = 0.f;
            #pragma unroll
            for (int ii = 0; ii < 10; ++ii) rs = DOT2(va[ii], va[ii], rs);
            const int dk = k - q*10;
            if (dk >= 0 && dk < 10) d = DOT2(va[dk], va[dk], 0.f);
            rs += __shfl_xor(rs, 1, 64); rs += __shfl_xor(rs, 2, 64);
            d  += __shfl_xor(d , 1, 64); d  += __shfl_xor(d , 2, 64);
            float T  = rs + SIGMA;
            float Is = rs - d + SIGMA;
            float cA = 2.f * INVLN2 / T;
            float cC = -2.f * INVLN2 * d / (Is * T);
            #pragma unroll
            for (int ii = 0; ii < 10; ++ii)
                vb[ii] = sh[OFF_SBA + (q*10+ii)*44 + k];
            h16x2 cvA = PK(cA, cA), cvC = PK(cC, cC);
            #pragma unroll
            for (int ii = 0; ii < 10; ++ii) {
                h16x2 c = ((q*10+ii) == k) ? cvA : cvC;
                sh[OFF_SAB + (q*10+ii)*44 + k] = va[ii] * c;
                sh[OFF_SBA + (q*10+ii)*44 + k] = vb[ii] * c;
            }
        }
        __syncthreads();                                   // (2)

        // ---- B: G = H @ S' - cp*W  (tile 2n x 5c; W from regs)
        float gr[2][5] = {}, gi[2][5] = {};
        #pragma unroll 2
        for (int kb = 0; kb < 10; ++kb) {
            h16x8 hA = *(const h16x8*)(sh + OFF_H + (n0  )*44 + kb*4);
            h16x8 hB = *(const h16x8*)(sh + OFF_H + (n0+1)*44 + kb*4);
            #pragma unroll
            for (int j = 0; j < 5; ++j) {
                h16x8 sa = *(const h16x8*)(sh + OFF_SAB + (c0+j)*44 + kb*4);
                h16x8 sb = *(const h16x8*)(sh + OFF_SBA + (c0+j)*44 + kb*4);
                #pragma unroll
                for (int kk = 0; kk < 4; ++kk) {
                    h16x2 s1 = GET8(sa,kk), s2 = GET8(sb,kk);
                    h16x2 a_ = GET8(hA,kk), b_ = GET8(hB,kk);
                    gr[0][j] = DOT2(a_, s1, gr[0][j]);
                    gi[0][j] = DOT2(a_, s2, gi[0][j]);
                    gr[1][j] = DOT2(b_, s1, gr[1][j]);
                    gi[1][j] = DOT2(b_, s2, gi[1][j]);
                }
            }
        }
        #pragma unroll
        for (int i = 0; i < 2; ++i)
            #pragma unroll
            for (int j = 0; j < 5; ++j) {
                gr[i][j] -= cp * Wr[i][j];
                gi[i][j] -= cp * Wi[i][j];
            }
        __syncthreads();                                   // (3) S reads done

        // G (m-pair packed, transposed) into dead S region; U[t] into sUp
        #pragma unroll
        for (int j = 0; j < 5; ++j) {
            sh[OFF_SAB + (c0+j)*34 + nn0] = PK(gr[0][j], gr[1][j]);
            sh[OFF_SBA + (c0+j)*34 + nn0] = PK(gi[0][j], gi[1][j]);
        }
        #pragma unroll
        for (int j = 0; j < 8; ++j) {
            int e = tid + j*256;                 // (n, mm)
            int n = e >> 5, mm = e & 31;
            sh[OFF_UP + n*34 + mm] = PK(ureg[j].x, ureg[j].y);
        }
        __syncthreads();                                   // (4) G, U visible

        // ---- C: Ug = U @ G; W update in regs; power fold; packed W -> LDS
        {
            float ur[2][5] = {}, ui[2][5] = {};
            #pragma unroll 2
            for (int mb = 0; mb < 16; ++mb) {
                const int mm0 = 2*mb;
                h16x4 u0v = *(const h16x4*)(sh + OFF_UP + (n0  )*34 + mm0);
                h16x4 u1v = *(const h16x4*)(sh + OFF_UP + (n0+1)*34 + mm0);
                h16x2 u0a = GET4(u0v,0), u0b = GET4(u0v,1);
                h16x2 u1a = GET4(u1v,0), u1b = GET4(u1v,1);
                #pragma unroll
                for (int j = 0; j < 5; ++j) {
                    h16x4 gv = *(const h16x4*)(sh + OFF_SAB + (c0+j)*34 + mm0);
                    h16x4 qv = *(const h16x4*)(sh + OFF_SBA + (c0+j)*34 + mm0);
                    h16x2 g0 = GET4(gv,0), g1 = GET4(gv,1);
                    h16x2 q0 = GET4(qv,0), q1 = GET4(qv,1);
                    ur[0][j] = DOT2(u0a, g0, DOT2(u0b, g1, ur[0][j]));
                    ui[0][j] = DOT2(u0a, q0, DOT2(u0b, q1, ui[0][j]));
                    ur[1][j] = DOT2(u1a, g0, DOT2(u1b, g1, ur[1][j]));
                    ui[1][j] = DOT2(u1a, q0, DOT2(u1b, q1, ui[1][j]));
                }
            }
            float ps2 = 0.f;
            #pragma unroll
            for (int i = 0; i < 2; ++i)
                #pragma unroll
                for (int j = 0; j < 5; ++j) {
                    float stepr = ur[i][j] - ui[i][j];
                    float stepi = ui[i][j] + ur[i][j];
                    float wr = Wr[i][j] - etat*stepr + breg[i][j];
                    float wi = Wi[i][j] - etat*stepi;
                    Wr[i][j] = wr; Wi[i][j] = wi;
                    sh[OFF_WAB + (n0+i)*40 + c0+j] = PK(wr,  wi);
                    sh[OFF_WBA + (n0+i)*40 + c0+j] = PK(wi, -wr);
                    ps2 += wr*wr + wi*wi;
                }
            #pragma unroll
            for (int off = 32; off; off >>= 1) ps2 += __shfl_down(ps2, off, 64);
            if ((tid & 63) == 0) sRed[wid] = ps2;
        }
        __syncthreads();                                   // (5)
    }

    // ---- final normalization from registers
    const float pwf   = sRed[0] + sRed[1] + sRed[2] + sRed[3];
    const float scale = 1.0f / (sqrtf(pwf) + 1e-6f);

    if (outFloats >= 2 * NBATCH * NT * KK) {
        float2* ob = (float2*)(gOut + (size_t)bb * NT * KK * 2);
        #pragma unroll
        for (int i = 0; i < 2; ++i)
            #pragma unroll
            for (int j = 0; j < 5; ++j) {
                float2 v; v.x = Wr[i][j]*scale; v.y = Wi[i][j]*scale;
                ob[(n0+i)*KK + c0 + j] = v;
            }
    } else {
        float* ob = gOut + (size_t)bb * NT * KK;
        #pragma unroll
        for (int i = 0; i < 2; ++i)
            #pragma unroll
            for (int j = 0; j < 5; ++j)
                ob[(n0+i)*KK + c0 + j] = Wr[i][j] * scale;
    }
}

extern "C" void kernel_launch(void* const* d_in, const int* in_sizes, int n_in,
                              void* d_out, int out_size, void* d_ws, size_t ws_size,
                              hipStream_t stream) {
    (void)in_sizes; (void)n_in; (void)d_ws; (void)ws_size;
    const float* Hr  = (const float*)d_in[0];
    const float* Hi  = (const float*)d_in[1];
    const float* eta = (const float*)d_in[2];
    const float* U   = (const float*)d_in[3];
    const float* b   = (const float*)d_in[4];
    float* out = (float*)d_out;
    gpnet_kernel<<<NBATCH, 256, 0, stream>>>(Hr, Hi, eta, U, b, out, out_size);
}